// Round 4
// baseline (721.638 us; speedup 1.0000x reference)
//
#include <hip/hip_runtime.h>
#include <cmath>
#include <cstdint>

#pragma clang fp contract(off)

#define B_ 2
#define N_ 65536
#define M_ 128
#define K_ 2048
#define S_ 6
#define NBLK 256          /* classify/compact blocks per batch */
#define CT 256            /* classify/compact threads per block */
#define FPS_T 512         /* threads per FPS chain (8 waves) */
#define PAIR_T 1024       /* two chains fused per block */
#define NW 8              /* waves per chain */
#define RMAX 8            /* per-thread point slots */
#define CAP (FPS_T * RMAX)  /* 4096 points max per chain for register path */

#define PI_F 3.14159265358979323846f
#define SS_F 1.0471975511965976f   /* (float)(2.0*pi/6) */

// Wave-wide max of 64-bit keys via DPP (VALU latency, not DS latency).
// Lane 63 holds the result. Identity: key==0 (bound_ctrl zero-fill loses).
__device__ __forceinline__ unsigned long long wave_max_u64_dpp(unsigned long long key) {
#define DPP_STEP(CTRL)                                                          \
    {                                                                           \
        unsigned lo = (unsigned)key, hi = (unsigned)(key >> 32);                \
        unsigned olo = (unsigned)__builtin_amdgcn_update_dpp(0, (int)lo, CTRL, 0xf, 0xf, true); \
        unsigned ohi = (unsigned)__builtin_amdgcn_update_dpp(0, (int)hi, CTRL, 0xf, 0xf, true); \
        unsigned long long o = ((unsigned long long)ohi << 32) | olo;           \
        if (o > key) key = o;                                                   \
    }
    DPP_STEP(0x111)  /* row_shr:1  */
    DPP_STEP(0x112)  /* row_shr:2  */
    DPP_STEP(0x114)  /* row_shr:4  */
    DPP_STEP(0x118)  /* row_shr:8  */
    DPP_STEP(0x142)  /* row_bcast:15 */
    DPP_STEP(0x143)  /* row_bcast:31 */
#undef DPP_STEP
    return key;
}

// ------------------------------------------------------------ classify ----
__global__ __launch_bounds__(CT)
void k_classify(const float* __restrict__ points, const float* __restrict__ rois,
                int* __restrict__ sec_id, int* __restrict__ blkcnt) {
    __shared__ float4 sroi[M_];
    __shared__ int lc[8];
    int blk = blockIdx.x;
    int gid = blk * CT + threadIdx.x;
    int b = gid >> 16;                       // N_ = 65536
    if (threadIdx.x < M_) {
        const float* r = rois + ((size_t)b * M_ + threadIdx.x) * 7;
        float cz = r[2] + r[5] * 0.5f;       // geometric center
        float hx = r[3] * 0.5f, hy = r[4] * 0.5f, hz = r[5] * 0.5f;
        sroi[threadIdx.x] = make_float4(r[0], r[1], cz, sqrtf((hx*hx + hy*hy) + hz*hz));
    }
    if (threadIdx.x < 8) lc[threadIdx.x] = 0;
    __syncthreads();

    const float* p = points + (size_t)gid * 3;
    float px = p[0], py = p[1], pz = p[2];
    float best = 1e30f; int bi = 0;
    for (int m = 0; m < M_; m++) {
        float4 c = sroi[m];
        float dx = px - c.x, dy = py - c.y, dz = pz - c.z;
        float d = sqrtf((dx*dx + dy*dy) + dz*dz);
        if (d < best) { best = d; bi = m; }  // strict < : first argmin
    }
    bool valid = best < (sroi[bi].w + 1.6f);

    float a = atan2f(py, px) + PI_F;
    float fs = floorf(a / SS_F);
    fs = fminf(fmaxf(fs, 0.0f), 6.0f);
    int sec = (int)fs;

    sec_id[gid] = valid ? sec : -1;
    if (valid) atomicAdd(&lc[sec], 1);
    __syncthreads();
    if (threadIdx.x < 8) blkcnt[blk * 8 + threadIdx.x] = lc[threadIdx.x];
}

// ---------------------------------------------------------------- plan ----
__global__ void k_plan(const int* __restrict__ blkcnt, int* __restrict__ bbase,
                       int* __restrict__ cnt, int* __restrict__ offv,
                       int* __restrict__ n_needed, int* __restrict__ sec_base,
                       int* __restrict__ s_total) {
    __shared__ int scnt[2][8];
    int t = threadIdx.x;
    if (t < 16) scnt[t >> 3][t & 7] = 0;
    __syncthreads();
    if (t < 14) {
        int b = t / 7, s = t % 7;
        int run = 0;
        #pragma unroll 16
        for (int j = 0; j < NBLK; j++) {
            int blk = b * NBLK + j;
            int c = blkcnt[blk * 8 + s];
            if (s < 6) bbase[blk * 6 + s] = run;
            run += c;
        }
        scnt[b][s] = run;
        cnt[b * 8 + s] = run;
    }
    __syncthreads();
    if (t < B_) {
        int b = t;
        int total = 0;
        for (int s = 0; s < 7; s++) total += scnt[b][s];
        if (total < 1) total = 1;
        int sb = 0, snk = 0;
        for (int s = 0; s < 6; s++) {
            int cs = scnt[b][s];
            int nk = (int)ceilf((float)cs * 2048.0f / (float)total);  // f32 semantics
            if (nk > cs) nk = cs;
            offv[b * 6 + s] = snk;
            int need = 0;
            if (snk < K_) { need = K_ - snk; if (need > nk) need = nk; }
            n_needed[b * 6 + s] = need;
            sec_base[b * 6 + s] = sb;
            sb += cs; snk += nk;
        }
        s_total[b] = (snk < 1) ? 1 : snk;
    }
}

// ------------------------------------------------------------- compact ----
__global__ __launch_bounds__(CT)
void k_compact(const float* __restrict__ points, const int* __restrict__ sec_id,
               const int* __restrict__ sec_base, const int* __restrict__ bbase,
               int* __restrict__ comp_idx, float4* __restrict__ comp_xyz) {
    __shared__ int lc[4 * 6];
    __shared__ int sbase[6], blkb[6];
    int blk = blockIdx.x;
    int b = blk >> 8;                         // NBLK = 256 blocks per batch
    int tid = threadIdx.x, lane = tid & 63, wid = tid >> 6;
    if (tid < 6) sbase[tid] = sec_base[b * 6 + tid];
    else if (tid >= 64 && tid < 70) blkb[tid - 64] = bbase[blk * 6 + (tid - 64)];
    int gid = blk * CT + tid;
    int sec = sec_id[gid];
    unsigned long long mymask = 0;
    for (int s = 0; s < 6; s++) {
        unsigned long long m = __ballot(sec == s);
        if (sec == s) mymask = m;
        if (lane == 0) lc[wid * 6 + s] = __popcll(m);
    }
    __syncthreads();
    if (sec >= 0 && sec < 6) {
        int woff = 0;
        for (int w = 0; w < wid; w++) woff += lc[w * 6 + sec];
        int rank = __popcll(mymask & ((1ull << lane) - 1ull));
        int addr = b * N_ + sbase[sec] + blkb[sec] + woff + rank;
        const float* p = points + (size_t)gid * 3;
        comp_idx[addr] = gid & (N_ - 1);
        comp_xyz[addr] = make_float4(p[0], p[1], p[2], 0.0f);
    }
}

// ----------------------------------------------------------------- fps ----
// TWO independent FPS chains fused per block (1024 thr = 2 x 8 waves).
// Waves 0-7 run chain blockIdx.x (b=0), waves 8-15 run chain blockIdx.x+6
// (b=1). Rationale: within one chain all waves advance in LOCKSTEP (one
// barrier per pick), so they cannot hide the post-barrier serial chain
// (DPP ~120cy + skey read ~120cy + tree + dependent sxyz[bix] read ~120cy
// = ~490cy/pick of fixed latency, the ~46% stall measured in round 3).
// Two INDEPENDENT chains on the same CU overlap: while half A sits in its
// reduce latency, half B's waves issue on the same SIMDs. Per-half logic
// is byte-identical to the verified round-3 kernel (same slot loop, same
// 4-chain carry + tree, same tie-break keys) -> picks are bit-exact.
// Shared barrier cadence: loop to max(needA, needB); a finished/dead half
// idles through barriers (all threads always reach every __syncthreads).
__global__ __launch_bounds__(PAIR_T)
void k_fps(const int* __restrict__ cnt, const int* __restrict__ sec_base,
           const int* __restrict__ offv, const int* __restrict__ n_needed,
           const float4* __restrict__ comp_xyz,
           float* __restrict__ dmin_g, int* __restrict__ buf) {
    __shared__ float4 sxyz[2][CAP];                 // 128 KB
    __shared__ int pick_lds[2][K_];                 // 16 KB
    __shared__ unsigned long long skey[2][2][NW];   // 256 B
    int tid = threadIdx.x;
    int half = tid >> 9;                  // 0: chain c0, 1: chain c1
    int ltid = tid & (FPS_T - 1);
    int lane = tid & 63;
    int w8 = (tid >> 6) & 7;              // wave index within half

    int c0 = blockIdx.x, c1 = blockIdx.x + S_;      // pair across batches
    int n0 = n_needed[(c0 / S_) * 6 + (c0 % S_)];
    int n1 = n_needed[(c1 / S_) * 6 + (c1 % S_)];
    int kmax = n0 > n1 ? n0 : n1;
    if (kmax <= 0) return;                // uniform over whole block

    int chain = half ? c1 : c0;
    int b = chain / S_, s = chain % S_;
    int need = half ? n1 : n0;
    int cs = cnt[b * 8 + s];
    int base = b * N_ + sec_base[b * 6 + s];
    const float4* cxyz = comp_xyz + base;
    int off = b * K_ + offv[b * 6 + s];
    float* dm = dmin_g + base;
    bool fast = (cs <= CAP);              // uniform within half

    // ---- stage points into registers + LDS mirror (fast path) ----
    float px[RMAX], py[RMAX], pz[RMAX], dmv[RMAX];
    if (fast && need > 0) {
        #pragma unroll
        for (int r = 0; r < RMAX; r++) {
            if (r * FPS_T < cs) {
                int i = ltid + r * FPS_T;
                if (i < cs) {
                    float4 q = cxyz[i];
                    sxyz[half][i] = q;
                    px[r] = q.x; py[r] = q.y; pz[r] = q.z;
                    dmv[r] = 1e10f;
                }
            }
        }
    }
    if (ltid == 0) pick_lds[half][0] = 0;  // first pick = first point
    __syncthreads();
    float lx = 0.0f, ly = 0.0f, lz = 0.0f;
    if (need > 0) {
        if (fast) { float4 l4 = sxyz[half][0]; lx = l4.x; ly = l4.y; lz = l4.z; }
        else      { float4 l4 = cxyz[0];       lx = l4.x; ly = l4.y; lz = l4.z; }
    }

    #pragma unroll 1
    for (int k = 1; k < kmax; k++) {
        unsigned long long key = 0;
        if (k < need) {
            if (fast) {
                unsigned long long t[4] = {0ull, 0ull, 0ull, 0ull};
                #pragma unroll
                for (int r = 0; r < RMAX; r++) {
                    if (r * FPS_T < cs) {          // wave-uniform
                        int i = ltid + r * FPS_T;
                        if (i < cs) {
                            float dx = px[r] - lx, dy = py[r] - ly, dz = pz[r] - lz;
                            float d = (dx*dx + dy*dy) + dz*dz;    // contract off
                            float nd = fminf(dmv[r], d);
                            dmv[r] = nd;
                            unsigned long long kk =
                                ((unsigned long long)__float_as_uint(nd) << 32)
                                | (unsigned)(~(unsigned)i);
                            if (kk > t[r & 3]) t[r & 3] = kk;     // 4 parallel chains
                        }
                    }
                }
                unsigned long long ta = (t[1] > t[0]) ? t[1] : t[0];
                unsigned long long tb = (t[3] > t[2]) ? t[3] : t[2];
                key = (tb > ta) ? tb : ta;
            } else {
                // fallback: dmin in global (not taken for this data: cs<=CAP)
                #pragma unroll 1
                for (int i = ltid; i < cs; i += FPS_T) {
                    float4 q = cxyz[i];
                    float dx = q.x - lx, dy = q.y - ly, dz = q.z - lz;
                    float d = (dx*dx + dy*dy) + dz*dz;
                    float prev = (k == 1) ? 1e10f : dm[i];
                    float nd = fminf(prev, d);
                    dm[i] = nd;
                    unsigned long long kk =
                        ((unsigned long long)__float_as_uint(nd) << 32)
                        | (unsigned)(~(unsigned)i);
                    if (kk > key) key = kk;
                }
            }
        }
        key = wave_max_u64_dpp(key);       // all waves (dead: key=0, harmless)
        int par = k & 1;
        if (lane == 63) skey[half][par][w8] = key;
        __syncthreads();
        if (k < need) {
            unsigned long long q0 = skey[half][par][0], q1 = skey[half][par][1];
            unsigned long long q2 = skey[half][par][2], q3 = skey[half][par][3];
            unsigned long long q4 = skey[half][par][4], q5 = skey[half][par][5];
            unsigned long long q6 = skey[half][par][6], q7 = skey[half][par][7];
            q0 = (q1 > q0) ? q1 : q0;
            q2 = (q3 > q2) ? q3 : q2;
            q4 = (q5 > q4) ? q5 : q4;
            q6 = (q7 > q6) ? q7 : q6;
            q0 = (q2 > q0) ? q2 : q0;
            q4 = (q6 > q4) ? q6 : q4;
            unsigned long long bk = (q4 > q0) ? q4 : q0;
            int bix = (int)(~(unsigned)(bk & 0xFFFFFFFFull));
            if (ltid == 0) pick_lds[half][k] = bix;
            if (fast) {
                float4 n4 = sxyz[half][bix];          // LDS broadcast
                lx = n4.x; ly = n4.y; lz = n4.z;
            } else {
                float4 n4 = cxyz[bix];                // rare path
                lx = n4.x; ly = n4.y; lz = n4.z;
            }
        }
    }
    __syncthreads();
    // coalesced writeback of all picks (per half)
    if (need > 0) {
        #pragma unroll 1
        for (int i = ltid; i < need; i += FPS_T)
            buf[off + i] = base + pick_lds[half][i];
    }
}

// ----------------------------------------------------------------- out ----
__global__ void k_out(const float* __restrict__ points, const int* __restrict__ buf,
                      const int* __restrict__ comp_idx, const int* __restrict__ s_total,
                      float* __restrict__ out) {
    int i = blockIdx.x * 256 + threadIdx.x;
    if (i >= B_ * K_) return;
    int b = i / K_, j = i % K_;
    int st = s_total[b];
    int g = buf[b * K_ + (j % st)];          // compacted global slot
    int idx = comp_idx[g];                   // original point index
    const float* p = points + ((size_t)b * N_ + idx) * 3;
    float* o = out + (size_t)i * 3;
    o[0] = p[0]; o[1] = p[1]; o[2] = p[2];
}

// -------------------------------------------------------------- launch ----
extern "C" void kernel_launch(void* const* d_in, const int* in_sizes, int n_in,
                              void* d_out, int out_size, void* d_ws, size_t ws_size,
                              hipStream_t stream) {
    const float* points = (const float*)d_in[0];   // [B,N,3]
    const float* rois   = (const float*)d_in[1];   // [B,M,7]
    float* out = (float*)d_out;                    // [B,K,3]

    char* w = (char*)d_ws;
    auto carve = [&](size_t bytes) -> char* {
        char* p = w; w += (bytes + 255) & ~(size_t)255; return p;
    };
    int*    sec_id   = (int*)   carve((size_t)B_ * N_ * sizeof(int));
    int*    blkcnt   = (int*)   carve((size_t)B_ * NBLK * 8 * sizeof(int));
    int*    bbase    = (int*)   carve((size_t)B_ * NBLK * 6 * sizeof(int));
    int*    cnt      = (int*)   carve((size_t)B_ * 8 * sizeof(int));
    int*    offv     = (int*)   carve((size_t)B_ * 6 * sizeof(int));
    int*    n_needed = (int*)   carve((size_t)B_ * 6 * sizeof(int));
    int*    sec_base = (int*)   carve((size_t)B_ * 6 * sizeof(int));
    int*    s_total  = (int*)   carve((size_t)B_ * sizeof(int));
    int*    buf      = (int*)   carve((size_t)B_ * K_ * sizeof(int));
    int*    comp_idx = (int*)   carve((size_t)B_ * N_ * sizeof(int));
    float4* comp_xyz = (float4*)carve((size_t)B_ * N_ * sizeof(float4));
    float*  dmin_g   = (float*) carve((size_t)B_ * N_ * sizeof(float));

    hipLaunchKernelGGL(k_classify, dim3(B_ * NBLK), dim3(CT), 0, stream,
                       points, rois, sec_id, blkcnt);
    hipLaunchKernelGGL(k_plan, dim3(1), dim3(64), 0, stream,
                       blkcnt, bbase, cnt, offv, n_needed, sec_base, s_total);
    hipLaunchKernelGGL(k_compact, dim3(B_ * NBLK), dim3(CT), 0, stream,
                       points, sec_id, sec_base, bbase, comp_idx, comp_xyz);
    hipLaunchKernelGGL(k_fps, dim3((B_ * S_) / 2), dim3(PAIR_T), 0, stream,
                       cnt, sec_base, offv, n_needed, comp_xyz, dmin_g, buf);
    hipLaunchKernelGGL(k_out, dim3((B_ * K_ + 255) / 256), dim3(256), 0, stream,
                       points, buf, comp_idx, s_total, out);
}